// Round 6
// baseline (252.004 us; speedup 1.0000x reference)
//
#include <hip/hip_runtime.h>
#include <hip/hip_bf16.h>

// ---- types ----
typedef __bf16 bf16x8 __attribute__((ext_vector_type(8)));
typedef __bf16 bf16x4 __attribute__((ext_vector_type(4)));
typedef float  f32x4  __attribute__((ext_vector_type(4)));

#define MFMA16(a, b, c) __builtin_amdgcn_mfma_f32_16x16x32_bf16((a), (b), (c), 0, 0, 0)

// Problem constants
#define BATCH 16
#define SEQ   1024
#define VD    1024
#define TD    768
#define HDIM  512
#define MROWS (BATCH * SEQ)   // 16384

// s_waitcnt simm16: vmcnt[3:0]|[15:14], expcnt [6:4], lgkmcnt [11:8]
// vmcnt(0), expcnt/lgkmcnt masked (max):
#define WAIT_VM0 0x0F70

typedef __attribute__((address_space(1))) const unsigned int gas_uint;
typedef __attribute__((address_space(3))) unsigned int las_uint;

__device__ __forceinline__ void async_copy16(const void* g, void* l) {
    __builtin_amdgcn_global_load_lds((gas_uint*)g, (las_uint*)l, 16, 0, 0);
}

// Stage one 128x64 bf16 tile by ONE wave (16 DMA instr/lane), chunk-XOR
// swizzle on the GLOBAL side (LDS side must stay lane-linear).
__device__ __forceinline__ void stage_tile_wave(const __bf16* __restrict__ src,
                                                size_t ld, int row0, int k0,
                                                __bf16* __restrict__ buf, int lane) {
#pragma unroll
    for (int i = 0; i < 16; ++i) {
        const int c = i * 64 + lane;          // chunk slot 0..1023
        const int r = c >> 3;                 // row 0..127
        const int g = (c & 7) ^ (r & 7);      // swizzled global chunk
        async_copy16(&src[(size_t)(row0 + r) * ld + k0 + g * 8], &buf[i * 512]);
    }
}

// fragment read: row r, k-half h (0/1), quad fq -> chunk (h*4+fq)^(r&7)
__device__ __forceinline__ bf16x8 frag_read(const __bf16* __restrict__ buf,
                                            int r, int h, int fq) {
    return *reinterpret_cast<const bf16x8*>(&buf[(r * 8 + ((h * 4 + fq) ^ (r & 7))) * 8]);
}

__device__ __forceinline__ void spin_until(int* p, int target) {
    // all lanes spin on the same LDS address (broadcast, cheap)
    while (__hip_atomic_load(p, __ATOMIC_ACQUIRE, __HIP_MEMORY_SCOPE_WORKGROUP) < target)
        __builtin_amdgcn_s_sleep(1);
}
__device__ __forceinline__ void signal(int* p, int lane) {
    if (lane == 0)
        __hip_atomic_fetch_add(p, 1, __ATOMIC_RELEASE, __HIP_MEMORY_SCOPE_WORKGROUP);
}

// ---------------------------------------------------------------------------
// fp32 -> bf16 streaming convert (Xv, Xt, Wv, Wt), ~252 MB traffic
// ---------------------------------------------------------------------------
#define NC_XV (BATCH * SEQ * VD / 4)
#define NC_XT (BATCH * SEQ * TD / 4)
#define NC_WV (HDIM * VD / 4)
#define NC_WT (HDIM * TD / 4)
#define NC_TOTAL (NC_XV + NC_XT + NC_WV + NC_WT)

__global__ __launch_bounds__(256) void conv_kernel(
    const float* __restrict__ Xv, const float* __restrict__ Xt,
    const float* __restrict__ Wv, const float* __restrict__ Wt,
    __bf16* __restrict__ Xvb, __bf16* __restrict__ Xtb,
    __bf16* __restrict__ Wvb, __bf16* __restrict__ Wtb) {
    int i = blockIdx.x * 256 + threadIdx.x;
    if (i >= NC_TOTAL) return;
    const float* src;
    __bf16* dst;
    if (i < NC_XV)                 { src = Xv; dst = Xvb; }
    else if ((i -= NC_XV) < NC_XT) { src = Xt; dst = Xtb; }
    else if ((i -= NC_XT) < NC_WV) { src = Wv; dst = Wvb; }
    else { i -= NC_WV;               src = Wt; dst = Wtb; }
    const float4 x = reinterpret_cast<const float4*>(src)[i];
    bf16x4 p = {(__bf16)x.x, (__bf16)x.y, (__bf16)x.z, (__bf16)x.w};
    reinterpret_cast<bf16x4*>(dst)[i] = p;
}

// ---------------------------------------------------------------------------
// Projection GEMM (NT), producer-consumer wave specialization:
//   C[M][512] = X[M][K] * W[512][K]^T + bias -> bf16, + fused row-norm^2.
// 384 threads: wave0 stages A (X rows), wave1 stages B (W rows), waves 2..5
// compute (2x2 of 64x64, 4x4 MFMA 16x16x32). BK=64, NBUF=2, no barrier in
// the K-loop: LDS flags ready[s] (producers->consumers) / done[s] (back).
// ---------------------------------------------------------------------------
__global__ __launch_bounds__(384) void proj_kernel(
    const __bf16* __restrict__ Xvb, const __bf16* __restrict__ Wvb, const float* __restrict__ bv_,
    const __bf16* __restrict__ Xtb, const __bf16* __restrict__ Wtb, const float* __restrict__ bt_,
    __bf16* __restrict__ vout, __bf16* __restrict__ tout,
    float* __restrict__ vn2, float* __restrict__ tn2)
{
    // L = mlow + 8*( n + 4*( mhigh + 16*z ) ) -> same-m n-tiles share an XCD
    const int L     = blockIdx.x;
    const int mlow  = L & 7;
    const int n     = (L >> 3) & 3;
    const int mhigh = (L >> 5) & 15;
    const int z     = L >> 9;
    const int m0    = (mhigh * 8 + mlow) * 128;
    const int n0    = n * 128;

    const __bf16* X; const __bf16* Wb; const float* bias; __bf16* out; float* n2; int K;
    if (z == 0) { X = Xvb; Wb = Wvb; bias = bv_; out = vout; n2 = vn2; K = VD; }
    else        { X = Xtb; Wb = Wtb; bias = bt_; out = tout; n2 = tn2; K = TD; }

    __shared__ __bf16 As[2][128 * 64];
    __shared__ __bf16 Bs[2][128 * 64];
    __shared__ int ready[16];
    __shared__ int done[16];

    const int tid  = threadIdx.x;
    const int lane = tid & 63;
    const int wave = tid >> 6;
    if (tid < 16) { ready[tid] = 0; done[tid] = 0; }
    __syncthreads();

    const int nk = K >> 6;   // 16 (v) / 12 (t)

    if (wave < 2) {
        // ---------------- producers ----------------
        const __bf16* src = (wave == 0) ? X : Wb;
        const int row0    = (wave == 0) ? m0 : n0;
        for (int s = 0; s < nk; ++s) {
            if (s >= 2) spin_until(&done[s - 2], 4);
            stage_tile_wave(src, K, row0, s << 6, (wave == 0) ? As[s & 1] : Bs[s & 1], lane);
            __builtin_amdgcn_s_waitcnt(WAIT_VM0);
            signal(&ready[s], lane);
        }
    } else {
        // ---------------- consumers ----------------
        const int cw = wave - 2;
        const int wr = cw >> 1, wc = cw & 1;
        const int fr = lane & 15, fq = lane >> 4;
        f32x4 acc[4][4] = {};

        for (int s = 0; s < nk; ++s) {
            spin_until(&ready[s], 2);
            const __bf16* Ab = As[s & 1];
            const __bf16* Bb = Bs[s & 1];
#pragma unroll
            for (int h = 0; h < 2; ++h) {
                bf16x8 a[4], b[4];
#pragma unroll
                for (int tm = 0; tm < 4; ++tm)
                    a[tm] = frag_read(Ab, wr * 64 + tm * 16 + fr, h, fq);
#pragma unroll
                for (int tn = 0; tn < 4; ++tn)
                    b[tn] = frag_read(Bb, wc * 64 + tn * 16 + fr, h, fq);
#pragma unroll
                for (int tm = 0; tm < 4; ++tm)
#pragma unroll
                    for (int tn = 0; tn < 4; ++tn)
                        acc[tm][tn] = MFMA16(a[tm], b[tn], acc[tm][tn]);
            }
            signal(&done[s], lane);
        }

        // epilogue: +bias, bf16 store, fused partial row-norm^2
        float bc[4];
#pragma unroll
        for (int tn = 0; tn < 4; ++tn)
            bc[tn] = bias[n0 + wc * 64 + tn * 16 + fr];

#pragma unroll
        for (int tm = 0; tm < 4; ++tm) {
            const int rowb = m0 + wr * 64 + tm * 16 + fq * 4;
#pragma unroll
            for (int r = 0; r < 4; ++r) {
                float s = 0.f;
#pragma unroll
                for (int tn = 0; tn < 4; ++tn) {
                    const float e = acc[tm][tn][r] + bc[tn];
                    out[(size_t)(rowb + r) * HDIM + n0 + wc * 64 + tn * 16 + fr] = (__bf16)e;
                    s = fmaf(e, e, s);
                }
                s += __shfl_xor(s, 1);
                s += __shfl_xor(s, 2);
                s += __shfl_xor(s, 4);
                s += __shfl_xor(s, 8);
                if (fr == 0) atomicAdd(&n2[rowb + r], s);
            }
        }
    }
}

// ---------------------------------------------------------------------------
// Batched dots GEMM (NT), same producer-consumer structure:
//   out[b][i][j] = v.t / max(sqrt(vn2_i*tn2_j), eps)
// 128x128 tile, K=512 -> 8 steps. Batch-colocating XCD swizzle.
// ---------------------------------------------------------------------------
__global__ __launch_bounds__(384) void dots_kernel(const __bf16* __restrict__ v,
                                                   const __bf16* __restrict__ t,
                                                   const float* __restrict__ vn2,
                                                   const float* __restrict__ tn2,
                                                   float* __restrict__ out) {
    __shared__ __bf16 As[2][128 * 64];
    __shared__ __bf16 Bs[2][128 * 64];
    __shared__ int ready[16];
    __shared__ int done[16];

    // L = (b&7) + 8*( j + 8*( i + 8*(b>>3) ) ) -> same-batch blocks share an XCD
    const int L  = blockIdx.x;
    const int b  = (L & 7) + ((L >> 9) << 3);
    const int j0 = ((L >> 3) & 7) * 128;
    const int i0 = ((L >> 6) & 7) * 128;

    const __bf16* vb = v + (size_t)b * SEQ * HDIM;
    const __bf16* tb = t + (size_t)b * SEQ * HDIM;

    const int tid  = threadIdx.x;
    const int lane = tid & 63;
    const int wave = tid >> 6;
    if (tid < 16) { ready[tid] = 0; done[tid] = 0; }
    __syncthreads();

    const int nk = HDIM >> 6;   // 8

    if (wave < 2) {
        const __bf16* src = (wave == 0) ? vb : tb;
        const int row0    = (wave == 0) ? i0 : j0;
        for (int s = 0; s < nk; ++s) {
            if (s >= 2) spin_until(&done[s - 2], 4);
            stage_tile_wave(src, HDIM, row0, s << 6, (wave == 0) ? As[s & 1] : Bs[s & 1], lane);
            __builtin_amdgcn_s_waitcnt(WAIT_VM0);
            signal(&ready[s], lane);
        }
    } else {
        const int cw = wave - 2;
        const int wr = cw >> 1, wc = cw & 1;
        const int fr = lane & 15, fq = lane >> 4;
        f32x4 acc[4][4] = {};

        for (int s = 0; s < nk; ++s) {
            spin_until(&ready[s], 2);
            const __bf16* Ab = As[s & 1];
            const __bf16* Bb = Bs[s & 1];
#pragma unroll
            for (int h = 0; h < 2; ++h) {
                bf16x8 a[4], bfr[4];
#pragma unroll
                for (int tm = 0; tm < 4; ++tm)
                    a[tm] = frag_read(Ab, wr * 64 + tm * 16 + fr, h, fq);
#pragma unroll
                for (int tn = 0; tn < 4; ++tn)
                    bfr[tn] = frag_read(Bb, wc * 64 + tn * 16 + fr, h, fq);
#pragma unroll
                for (int tm = 0; tm < 4; ++tm)
#pragma unroll
                    for (int tn = 0; tn < 4; ++tn)
                        acc[tm][tn] = MFMA16(a[tm], bfr[tn], acc[tm][tn]);
            }
            signal(&done[s], lane);
        }

        float vr2[16];
#pragma unroll
        for (int tm = 0; tm < 4; ++tm)
#pragma unroll
            for (int r = 0; r < 4; ++r)
                vr2[tm * 4 + r] = vn2[b * SEQ + i0 + wr * 64 + tm * 16 + fq * 4 + r];

        float* outb = out + ((size_t)b << 20);
#pragma unroll
        for (int tn = 0; tn < 4; ++tn) {
            const int j     = j0 + wc * 64 + tn * 16 + fr;
            const float tj2 = tn2[b * SEQ + j];
#pragma unroll
            for (int tm = 0; tm < 4; ++tm) {
                const int ib = i0 + wr * 64 + tm * 16 + fq * 4;
#pragma unroll
                for (int r = 0; r < 4; ++r) {
                    const float denom = fmaxf(sqrtf(vr2[tm * 4 + r] * tj2), 1e-8f);
                    outb[(size_t)(ib + r) * SEQ + j] = acc[tm][tn][r] * __builtin_amdgcn_rcpf(denom);
                }
            }
        }
    }
}

// ---------------------------------------------------------------------------
extern "C" void kernel_launch(void* const* d_in, const int* in_sizes, int n_in,
                              void* d_out, int out_size, void* d_ws, size_t ws_size,
                              hipStream_t stream) {
    const float* Xv = (const float*)d_in[0];
    const float* Xt = (const float*)d_in[1];
    const float* Wv = (const float*)d_in[2];
    const float* bv = (const float*)d_in[3];
    const float* Wt = (const float*)d_in[4];
    const float* bt = (const float*)d_in[5];
    float* out = (float*)d_out;

    char* ws = (char*)d_ws;
    size_t off = 0;
    __bf16* v   = (__bf16*)(ws + off); off += (size_t)MROWS * HDIM * 2;    // 16 MiB
    __bf16* t   = (__bf16*)(ws + off); off += (size_t)MROWS * HDIM * 2;    // 16 MiB
    __bf16* Xvb = (__bf16*)(ws + off); off += (size_t)MROWS * VD * 2;      // 32 MiB
    __bf16* Xtb = (__bf16*)(ws + off); off += (size_t)MROWS * TD * 2;      // 24 MiB
    __bf16* Wvb = (__bf16*)(ws + off); off += (size_t)HDIM * VD * 2;       // 1 MiB
    __bf16* Wtb = (__bf16*)(ws + off); off += (size_t)HDIM * TD * 2;       // 0.75 MiB
    float*  vn2 = (float*)(ws + off);  off += (size_t)MROWS * 4;           // 64 KiB
    float*  tn2 = (float*)(ws + off);  off += (size_t)MROWS * 4;           // 64 KiB

    hipMemsetAsync(vn2, 0, (size_t)2 * MROWS * 4, stream);

    // 0) fp32 -> bf16 streaming convert
    conv_kernel<<<(NC_TOTAL + 255) / 256, 256, 0, stream>>>(Xv, Xt, Wv, Wt, Xvb, Xtb, Wvb, Wtb);

    // 1) projections + fused norms: 1024 swizzled blocks (512 v + 512 t)
    proj_kernel<<<1024, 384, 0, stream>>>(Xvb, Wvb, bv, Xtb, Wtb, bt, v, t, vn2, tn2);

    // 2) batched dots + normalize: 1024 swizzled blocks
    dots_kernel<<<1024, 384, 0, stream>>>(v, t, vn2, tn2, out);
}